// Round 11
// baseline (122.828 us; speedup 1.0000x reference)
//
// v11: float2 x loads — test of the per-CU miss-concurrency theory
// (BW ∝ bytes per load instruction). Block = (nt, 98-col half-row),
// 8 waves = 8 ch-chunks, 49 lanes x dwordx2. Grid 256 = 1 block/CU.
// Numerics bit-identical to v4/v8. k_conv = v4 scalar (proven best).
#include <hip/hip_runtime.h>

#define T 8
#define C 512
#define HW 196
#define NSEG 16                  // n
#define NT (NSEG * T)            // 128
#define B_TOT (NSEG * HW)        // 3136
#define NH 4
#define KK 5
#define NO 20                    // NH*KK
#define S_SPLIT 8                // channel chunks = waves per block
#define CCH (C / S_SPLIT)        // 64 channels per chunk
#define COLS 98                  // columns per block (half row)
#define LDSC 100                 // padded col dim for LDS

// ---------------------------------------------------------------------------
// Kernel 1: fused logits + LDS chunk-reduction + softmax -> weights.
// Grid 256 x 512thr; wave w = chunk w (readfirstlane-pinned -> scalar W).
// Each lane owns TWO adjacent hw columns -> dwordx2 x loads (392 B/instr).
// ---------------------------------------------------------------------------
__global__ __launch_bounds__(512, 2) void k_weights(const float* __restrict__ x,
                                                    const float* __restrict__ W,
                                                    float* __restrict__ wgt) {
    __shared__ float plds[S_SPLIT][NO][LDSC];   // 64000 B

    const int tid  = threadIdx.x;
    const int lane = tid & 63;
    const int sch  = tid >> 6;                  // wave index = channel chunk
    const int cbase = __builtin_amdgcn_readfirstlane(sch * CCH);  // SGPR

    const int nt  = blockIdx.x >> 1;            // block-uniform
    const int hw0 = (blockIdx.x & 1) * COLS;    // 0 or 98
    const int le  = (lane < 49) ? lane : 48;    // effective lane (clamp)
    const int hw  = hw0 + 2 * le;               // 8-B aligned column pair

    const float* xp = x + ((size_t)nt * C + cbase) * HW + hw;
    const float* Wb = W + cbase;                // wave-uniform base -> s_load

    float2 acc[NO];
#pragma unroll
    for (int o = 0; o < NO; ++o) acc[o] = make_float2(0.f, 0.f);

    // dist-1 prefetch (proven sufficient), float2 per channel
    float2 xv[8], xn[8];
#pragma unroll
    for (int u = 0; u < 8; ++u) xv[u] = *(const float2*)(xp + u * HW);

#pragma unroll
    for (int c0 = 0; c0 < CCH; c0 += 8) {
        if (c0 + 8 < CCH) {
#pragma unroll
            for (int u = 0; u < 8; ++u)
                xn[u] = *(const float2*)(xp + (c0 + 8 + u) * HW);
        }
        const float* wr = Wb + c0;              // wave-uniform
#pragma unroll
        for (int o = 0; o < NO; ++o) {
#pragma unroll
            for (int u = 0; u < 8; ++u) {
                const float wv = wr[o * C + u];
                acc[o].x = fmaf(xv[u].x, wv, acc[o].x);
                acc[o].y = fmaf(xv[u].y, wv, acc[o].y);
            }
        }
#pragma unroll
        for (int u = 0; u < 8; ++u) xv[u] = xn[u];
    }

    // partials: lanes 0..48 store their column pair (float2, 8-B aligned)
    if (lane < 49) {
#pragma unroll
        for (int o = 0; o < NO; ++o)
            *(float2*)&plds[sch][o][2 * le] = acc[o];
    }
    __syncthreads();

    // reduce over chunks (s-order 0..7 -> numerics identical), softmax over
    // 5 taps. 392 threads: (head 0..3) x (col 0..97).
    if (tid < COLS * NH) {
        const int h   = tid / COLS;
        const int col = tid - h * COLS;
        const int t   = nt & (T - 1);
        const int n   = nt >> 3;                // nt / T
        const int b   = n * HW + hw0 + col;

        float lg[KK];
#pragma unroll
        for (int k = 0; k < KK; ++k) {
            float sm = 0.f;
#pragma unroll
            for (int s2 = 0; s2 < S_SPLIT; ++s2)
                sm += plds[s2][h * KK + k][col];
            lg[k] = sm;
        }

        float m = lg[0];
#pragma unroll
        for (int k = 1; k < KK; ++k) m = fmaxf(m, lg[k]);
        float e[KK];
        float sum = 0.f;
#pragma unroll
        for (int k = 0; k < KK; ++k) {
            e[k] = __expf(lg[k] - m);
            sum += e[k];
        }
        const float r = 1.f / sum;
#pragma unroll
        for (int k = 0; k < KK; ++k)
            wgt[((size_t)((t * NH + h) * KK + k)) * B_TOT + b] = e[k] * r;
    }
}

// ---------------------------------------------------------------------------
// Kernel 2: causal dynamic conv, one thread per (n, c, hw) — v4 scalar
// version verbatim (float2 variant measured worse; at ~8 µs floor,
// x re-read is L3-resident after k_weights).
// ---------------------------------------------------------------------------
__global__ __launch_bounds__(256) void k_conv(const float* __restrict__ x,
                                              const float* __restrict__ wgt,
                                              float* __restrict__ out) {
    const int idx = blockIdx.x * 256 + threadIdx.x;  // < 16*512*196
    const int hw  = idx % HW;
    const int t1  = idx / HW;          // n*C + c
    const int c   = t1 % C;
    const int n   = t1 / C;
    const int h   = c >> 7;            // head
    const int b   = n * HW + hw;

    float w[T][KK];
#pragma unroll
    for (int t = 0; t < T; ++t)
#pragma unroll
        for (int k = 0; k < KK; ++k)
            w[t][k] = wgt[((size_t)((t * NH + h) * KK + k)) * B_TOT + b];

    const size_t base = ((size_t)(n * T) * C + c) * HW + hw;
    float xv[T];
#pragma unroll
    for (int t = 0; t < T; ++t) xv[t] = x[base + (size_t)t * C * HW];

#pragma unroll
    for (int t = 0; t < T; ++t) {
        float acc = 0.f;
#pragma unroll
        for (int k = 0; k < KK; ++k) {
            const int j = t + k - 4;   // causal, zero-padded left
            if (j >= 0) acc = fmaf(w[t][k], xv[j], acc);
        }
        out[base + (size_t)t * C * HW] = acc;
    }
}

// ---------------------------------------------------------------------------
extern "C" void kernel_launch(void* const* d_in, const int* in_sizes, int n_in,
                              void* d_out, int out_size, void* d_ws, size_t ws_size,
                              hipStream_t stream) {
    const float* x = (const float*)d_in[0];   // (128, 512, 14, 14)
    const float* W = (const float*)d_in[1];   // (20, 512)
    float* out = (float*)d_out;               // (128, 512, 14, 14)

    float* wgt = (float*)d_ws;                // 160 * 3136 floats = 2 MB

    k_weights<<<dim3(NT * 2), 512, 0, stream>>>(x, W, wgt);   // 256 blocks
    k_conv<<<dim3((NSEG * C * HW) / 256), 256, 0, stream>>>(x, wgt, out);
}

// Round 12
// 117.472 us; speedup vs baseline: 1.0456x; 1.0456x over previous
//
// v12 = v4 verbatim (best measured: 116.3 µs). Wave-uniform scalar-W,
// dist-1 x prefetch, 392x512 grid, fused LDS reduce + softmax; v4 k_conv.
// Seven subsequent levers (v5-v11) all measured null/negative; reverting
// to the proven optimum.
#include <hip/hip_runtime.h>

#define T 8
#define C 512
#define HW 196
#define NSEG 16                  // n
#define NT (NSEG * T)            // 128
#define NCOL (NT * HW)           // 25088 (nt, hw) columns
#define B_TOT (NSEG * HW)        // 3136
#define NH 4
#define KK 5
#define NO 20                    // NH*KK
#define S_SPLIT 8                // channel chunks = waves per block
#define CCH (C / S_SPLIT)        // 64 channels per chunk
#define COLS 64                  // columns per k_weights block (= lanes)

// ---------------------------------------------------------------------------
// Kernel 1: fused logits + LDS chunk-reduction + softmax -> weights.
// Grid 392 x 512. Wave w = channel chunk w (W via s_load, readfirstlane-
// pinned). Dist-1 prefetch on x (dist-2 measured neutral).
// ---------------------------------------------------------------------------
__global__ __launch_bounds__(512) void k_weights(const float* __restrict__ x,
                                                 const float* __restrict__ W,
                                                 float* __restrict__ wgt) {
    __shared__ float plds[S_SPLIT][NO][COLS];   // 40960 B

    const int tid  = threadIdx.x;
    const int lane = tid & 63;                  // column within tile
    const int sch  = tid >> 6;                  // wave index = channel chunk
    const int cbase = __builtin_amdgcn_readfirstlane(sch * CCH);  // SGPR

    const int idx = blockIdx.x * COLS + lane;   // flattened (nt, hw)
    const int nt  = idx / HW;
    const int hw  = idx - nt * HW;

    const float* xp = x + ((size_t)nt * C + cbase) * HW + hw;
    const float* Wb = W + cbase;                // wave-uniform base -> s_load

    float acc[NO];
#pragma unroll
    for (int o = 0; o < NO; ++o) acc[o] = 0.f;

    float xv[8], xn[8];
#pragma unroll
    for (int u = 0; u < 8; ++u) xv[u] = xp[u * HW];

#pragma unroll
    for (int c0 = 0; c0 < CCH; c0 += 8) {
        if (c0 + 8 < CCH) {
#pragma unroll
            for (int u = 0; u < 8; ++u) xn[u] = xp[(c0 + 8 + u) * HW];
        }
        const float* wr = Wb + c0;              // wave-uniform
#pragma unroll
        for (int o = 0; o < NO; ++o) {
#pragma unroll
            for (int u = 0; u < 8; ++u)
                acc[o] = fmaf(xv[u], wr[o * C + u], acc[o]);
        }
#pragma unroll
        for (int u = 0; u < 8; ++u) xv[u] = xn[u];
    }

    // partials: lane-consecutive -> 2-way bank aliasing max (free on CDNA4)
#pragma unroll
    for (int o = 0; o < NO; ++o) plds[sch][o][lane] = acc[o];
    __syncthreads();

    // reduce over chunks (s-order 0..7 -> identical numerics), softmax over
    // 5 taps. 256 threads: (head 0..3) x (col 0..63).
    if (tid < COLS * NH) {
        const int col  = tid & 63;
        const int h    = tid >> 6;
        const int idx2 = blockIdx.x * COLS + col;
        const int nt2  = idx2 / HW;
        const int hw2  = idx2 - nt2 * HW;
        const int t    = nt2 & (T - 1);
        const int n    = nt2 / T;
        const int b    = n * HW + hw2;

        float lg[KK];
#pragma unroll
        for (int k = 0; k < KK; ++k) {
            float sm = 0.f;
#pragma unroll
            for (int s2 = 0; s2 < S_SPLIT; ++s2)
                sm += plds[s2][h * KK + k][col];
            lg[k] = sm;
        }

        float m = lg[0];
#pragma unroll
        for (int k = 1; k < KK; ++k) m = fmaxf(m, lg[k]);
        float e[KK];
        float sum = 0.f;
#pragma unroll
        for (int k = 0; k < KK; ++k) {
            e[k] = __expf(lg[k] - m);
            sum += e[k];
        }
        const float r = 1.f / sum;
#pragma unroll
        for (int k = 0; k < KK; ++k)
            wgt[((size_t)((t * NH + h) * KK + k)) * B_TOT + b] = e[k] * r;
    }
}

// ---------------------------------------------------------------------------
// Kernel 2: causal dynamic conv, one thread per (n, c, hw) — at its
// ~8 µs out-write floor (x re-read L2/L3-resident after k_weights).
// ---------------------------------------------------------------------------
__global__ __launch_bounds__(256) void k_conv(const float* __restrict__ x,
                                              const float* __restrict__ wgt,
                                              float* __restrict__ out) {
    const int idx = blockIdx.x * 256 + threadIdx.x;  // < 16*512*196
    const int hw  = idx % HW;
    const int t1  = idx / HW;          // n*C + c
    const int c   = t1 % C;
    const int n   = t1 / C;
    const int h   = c >> 7;            // head
    const int b   = n * HW + hw;

    float w[T][KK];
#pragma unroll
    for (int t = 0; t < T; ++t)
#pragma unroll
        for (int k = 0; k < KK; ++k)
            w[t][k] = wgt[((size_t)((t * NH + h) * KK + k)) * B_TOT + b];

    const size_t base = ((size_t)(n * T) * C + c) * HW + hw;
    float xv[T];
#pragma unroll
    for (int t = 0; t < T; ++t) xv[t] = x[base + (size_t)t * C * HW];

#pragma unroll
    for (int t = 0; t < T; ++t) {
        float acc = 0.f;
#pragma unroll
        for (int k = 0; k < KK; ++k) {
            const int j = t + k - 4;   // causal, zero-padded left
            if (j >= 0) acc = fmaf(w[t][k], xv[j], acc);
        }
        out[base + (size_t)t * C * HW] = acc;
    }
}

// ---------------------------------------------------------------------------
extern "C" void kernel_launch(void* const* d_in, const int* in_sizes, int n_in,
                              void* d_out, int out_size, void* d_ws, size_t ws_size,
                              hipStream_t stream) {
    const float* x = (const float*)d_in[0];   // (128, 512, 14, 14)
    const float* W = (const float*)d_in[1];   // (20, 512)
    float* out = (float*)d_out;               // (128, 512, 14, 14)

    float* wgt = (float*)d_ws;                // 160 * 3136 floats = 2 MB

    k_weights<<<dim3(NCOL / COLS), 512, 0, stream>>>(x, W, wgt);
    k_conv<<<dim3((NSEG * C * HW) / 256), 256, 0, stream>>>(x, wgt, out);
}